// Round 6
// baseline (67.479 us; speedup 1.0000x reference)
//
#include <hip/hip_runtime.h>
#include <hip/hip_bf16.h>

// GaussianSmoothing (2,1,192,192,192) f32, separable K=13 sigma=2.
// Pass 1 blur_w: one-shot elementwise W-blur (5 masked f4 loads -> 1 f4 out),
//   zero inter-step deps, latency hidden by pure TLP.   x -> d_out
// Pass 2 col_blur<H>: rolling-accumulator column march.  d_out -> d_ws
// Pass 3 col_blur<D>: rolling-accumulator column march.  d_ws -> d_out

#define DIM 192
#define DIM2 (192 * 192)
#define NIMG 2
#define TOTAL (NIMG * DIM * DIM2)   // 14,155,776 floats
#define NQ (TOTAL / 4)              // 3,538,944 float4 quads (48 per row)

#define GTAPS                                                     \
    constexpr float G[13] = {                                     \
        2.2159242e-03f, 8.7641505e-03f, 2.6995483e-02f,           \
        6.4758800e-02f, 1.2098536e-01f, 1.7603266e-01f,           \
        1.9947114e-01f, 1.7603266e-01f, 1.2098536e-01f,           \
        6.4758800e-02f, 2.6995483e-02f, 8.7641505e-03f,           \
        2.2159242e-03f };

// ---------------------------------------------------------------------------
// Pass 1: W-blur, one f4 output per thread. Window spans quads xq-2..xq+2 of
// the same 48-quad row; out-of-row quads clamped (always-valid address) and
// zeroed via 0/1 multipliers. All loads independent across the whole grid.
// Grid = NQ/256 = 13824 blocks.
// ---------------------------------------------------------------------------
__global__ __launch_bounds__(256) void blur_w(const float4* __restrict__ in,
                                              float4* __restrict__ out) {
    GTAPS
    const int q = blockIdx.x * 256 + threadIdx.x;   // global quad id
    const int xq = q % 48;
    const int rowbase = q - xq;

    float f[20];
#pragma unroll
    for (int d = 0; d < 5; ++d) {
        int qq = xq + d - 2;
        const float m = (qq >= 0 && qq < 48) ? 1.0f : 0.0f;
        qq = min(max(qq, 0), 47);
        float4 v = in[rowbase + qq];
        if (d != 2) { v.x *= m; v.y *= m; v.z *= m; v.w *= m; }
        *(float4*)&f[d * 4] = v;
    }

    float4 o;
    float* op = &o.x;
#pragma unroll
    for (int j = 0; j < 4; ++j) {
        float a = 0.0f;
#pragma unroll
        for (int k = 0; k < 13; ++k) a += G[k] * f[j + k + 2];
        op[j] = a;
    }
    out[q] = o;
}

// ---------------------------------------------------------------------------
// Passes 2/3: blur along an axis with f4-stride S. Each thread owns a float4
// column and marches 32 outputs (+12 halo) with 13 rolling f4 accumulators.
//   column c: base_f4 = (c / Q) * M + (c % Q)
//   H pass: Q=48 (quads/row),    M=9216 (plane, f4),  S=48 (row, f4)
//   D pass: Q=9216 (quads/plane), M=1769472 (img, f4), S=9216 (plane, f4)
// ncols = 18432; chunks = 6; block = 128 -> grid = 864.
// ---------------------------------------------------------------------------
template <int Q, int M, int S>
__global__ __launch_bounds__(128) void col_blur(const float4* __restrict__ in,
                                                float4* __restrict__ out) {
    GTAPS
    const int gt = blockIdx.x * 128 + threadIdx.x;
    const int chunk = gt / 18432;          // uniform per block (18432 % 128 == 0)
    const int c = gt % 18432;
    const int base = (c / Q) * M + (c % Q);
    const int d0 = chunk * 32;

    float4 acc[13];
#pragma unroll
    for (int j = 0; j < 13; ++j) acc[j] = make_float4(0.f, 0.f, 0.f, 0.f);

#pragma unroll
    for (int s = 0; s < 44; ++s) {
        const int i = d0 - 6 + s;
        float4 v = make_float4(0.f, 0.f, 0.f, 0.f);
        if (i >= 0 && i < DIM) v = in[base + i * S];
#pragma unroll
        for (int j = 0; j < 13; ++j) {
            const float g = G[12 - j];
            acc[j].x += g * v.x;
            acc[j].y += g * v.y;
            acc[j].z += g * v.z;
            acc[j].w += g * v.w;
        }
        if (s >= 12) out[base + (i - 6) * S] = acc[0];
#pragma unroll
        for (int j = 0; j < 12; ++j) acc[j] = acc[j + 1];
        acc[12] = make_float4(0.f, 0.f, 0.f, 0.f);
    }
}

extern "C" void kernel_launch(void* const* d_in, const int* in_sizes, int n_in,
                              void* d_out, int out_size, void* d_ws, size_t ws_size,
                              hipStream_t stream) {
    const float* x = (const float*)d_in[0];
    float* out = (float*)d_out;
    float* tmp = (float*)d_ws;  // 56.6 MB scratch

    // Pass 1: W axis one-shot, x -> out
    blur_w<<<NQ / 256, 256, 0, stream>>>((const float4*)x, (float4*)out);
    // Pass 2: H axis (stride 48 f4), out -> tmp
    col_blur<48, 9216, 48><<<864, 128, 0, stream>>>((const float4*)out, (float4*)tmp);
    // Pass 3: D axis (stride 9216 f4), tmp -> out
    col_blur<9216, 1769472, 9216><<<864, 128, 0, stream>>>((const float4*)tmp, (float4*)out);
}

// Round 7
// 66.228 us; speedup vs baseline: 1.0189x; 1.0189x over previous
//
#include <hip/hip_runtime.h>
#include <hip/hip_bf16.h>

// GaussianSmoothing (2,1,192,192,192) f32, separable K=13 sigma=2.
// Pass A blur_wh: fused W+H column-march, CH=8, depth-1 software-pipelined
//   prefetch of the 5 masked/clamped f4 loads. x -> d_ws
// Pass B col_blur<D>: rolling-accumulator column march. d_ws -> d_out

#define DIM 192
#define DIM2 (192 * 192)
#define NIMG 2
#define TOTAL (NIMG * DIM * DIM2)   // 14,155,776 floats

#define GTAPS                                                     \
    constexpr float G[13] = {                                     \
        2.2159242e-03f, 8.7641505e-03f, 2.6995483e-02f,           \
        6.4758800e-02f, 1.2098536e-01f, 1.7603266e-01f,           \
        1.9947114e-01f, 1.7603266e-01f, 1.2098536e-01f,           \
        6.4758800e-02f, 2.6995483e-02f, 8.7641505e-03f,           \
        2.2159242e-03f };

// ---------------------------------------------------------------------------
// Pass A: fused W+H. Column = (plane, xq): 384 planes x 48 quads = 18432
// columns; 24 y-chunks of 8 outputs (20 steps incl. 12-row halo).
// Depth-1 pipeline: loads for row s+1 issue before row s is consumed, into
// named registers (p0..p4 -> c0..c4 rotation, all static).
// Grid = 18432*24/256 = 1728 blocks x 256 (~6912 waves).
// ---------------------------------------------------------------------------
#define CH 8
#define NSTEP (CH + 12)   // 20

__global__ __launch_bounds__(256) void blur_wh(const float4* __restrict__ in,
                                               float4* __restrict__ out) {
    GTAPS
    const int gt = blockIdx.x * 256 + threadIdx.x;
    const int chunk = gt / 18432;        // uniform per block (18432 % 256 == 0)
    const int c = gt % 18432;
    const int plane = c / 48;
    const int xq = c % 48;
    const int base = plane * 9216;       // f4 units
    const int y0 = chunk * CH;

    // per-lane x-window masks and clamped quad offsets (loop-invariant)
    float xm0, xm1, xm3, xm4;
    int qc0, qc1, qc2, qc3, qc4;
    {
        int q;
        q = xq - 2; xm0 = (q >= 0) ? 1.0f : 0.0f; qc0 = max(q, 0);
        q = xq - 1; xm1 = (q >= 0) ? 1.0f : 0.0f; qc1 = max(q, 0);
        qc2 = xq;
        q = xq + 1; xm3 = (q < 48) ? 1.0f : 0.0f; qc3 = min(q, 47);
        q = xq + 2; xm4 = (q < 48) ? 1.0f : 0.0f; qc4 = min(q, 47);
    }

#define LOADROW(s, r0, r1, r2, r3, r4)                                        \
    {                                                                         \
        const int i_ = y0 - 6 + (s);                                          \
        const int ic_ = min(max(i_, 0), DIM - 1);                             \
        const float4* __restrict__ rp_ = in + base + ic_ * 48;                \
        r0 = rp_[qc0]; r1 = rp_[qc1]; r2 = rp_[qc2];                          \
        r3 = rp_[qc3]; r4 = rp_[qc4];                                         \
        r0.x *= xm0; r0.y *= xm0; r0.z *= xm0; r0.w *= xm0;                   \
        r1.x *= xm1; r1.y *= xm1; r1.z *= xm1; r1.w *= xm1;                   \
        r3.x *= xm3; r3.y *= xm3; r3.z *= xm3; r3.w *= xm3;                   \
        r4.x *= xm4; r4.y *= xm4; r4.z *= xm4; r4.w *= xm4;                   \
    }

    float4 acc[13];
#pragma unroll
    for (int j = 0; j < 13; ++j) acc[j] = make_float4(0.f, 0.f, 0.f, 0.f);

    float4 c0, c1, c2, c3, c4;      // current row (masked)
    float4 p0, p1, p2, p3, p4;      // prefetched next row
    LOADROW(0, c0, c1, c2, c3, c4)

#pragma unroll
    for (int s = 0; s < NSTEP; ++s) {
        if (s < NSTEP - 1) LOADROW(s + 1, p0, p1, p2, p3, p4)

        const int i = y0 - 6 + s;
        const float ym = (i >= 0 && i < DIM) ? 1.0f : 0.0f;

        float f[20];
        *(float4*)&f[0]  = c0;
        *(float4*)&f[4]  = c1;
        *(float4*)&f[8]  = c2;
        *(float4*)&f[12] = c3;
        *(float4*)&f[16] = c4;

        // W-blur this row's quad: f[m] = raw[4*xq - 8 + m] (x-masked)
        float4 w;
        float* wp = &w.x;
#pragma unroll
        for (int j = 0; j < 4; ++j) {
            float a = 0.0f;
#pragma unroll
            for (int k = 0; k < 13; ++k) a += G[k] * f[j + k + 2];
            wp[j] = a * ym;                 // y-validity folded here
        }

        // rolling H accumulation: acc[j] holds output row (i-6)+j, tap 12-j
#pragma unroll
        for (int j = 0; j < 13; ++j) {
            const float g = G[12 - j];
            acc[j].x += g * w.x;
            acc[j].y += g * w.y;
            acc[j].z += g * w.z;
            acc[j].w += g * w.w;
        }
        if (s >= 12) out[base + (y0 + s - 12) * 48 + xq] = acc[0];
#pragma unroll
        for (int j = 0; j < 12; ++j) acc[j] = acc[j + 1];
        acc[12] = make_float4(0.f, 0.f, 0.f, 0.f);

        c0 = p0; c1 = p1; c2 = p2; c3 = p3; c4 = p4;   // rotate pipeline
    }
#undef LOADROW
}

// ---------------------------------------------------------------------------
// Pass B: blur along D. Each thread owns a float4 column, marches 32 outputs
// (+12 halo) with 13 rolling float4 accumulators (fully unrolled).
//   D: Q=9216 (quads/plane), M=1769472 (img, f4), S=9216 (plane, f4)
// ncols = 18432; chunks = 6; block = 128 -> grid = 864.
// ---------------------------------------------------------------------------
template <int Q, int M, int S>
__global__ __launch_bounds__(128) void col_blur(const float4* __restrict__ in,
                                                float4* __restrict__ out) {
    GTAPS
    const int gt = blockIdx.x * 128 + threadIdx.x;
    const int chunk = gt / 18432;          // uniform per block (18432 % 128 == 0)
    const int c = gt % 18432;
    const int base = (c / Q) * M + (c % Q);
    const int d0 = chunk * 32;

    float4 acc[13];
#pragma unroll
    for (int j = 0; j < 13; ++j) acc[j] = make_float4(0.f, 0.f, 0.f, 0.f);

#pragma unroll
    for (int s = 0; s < 44; ++s) {
        const int i = d0 - 6 + s;
        float4 v = make_float4(0.f, 0.f, 0.f, 0.f);
        if (i >= 0 && i < DIM) v = in[base + i * S];
#pragma unroll
        for (int j = 0; j < 13; ++j) {
            const float g = G[12 - j];
            acc[j].x += g * v.x;
            acc[j].y += g * v.y;
            acc[j].z += g * v.z;
            acc[j].w += g * v.w;
        }
        if (s >= 12) out[base + (i - 6) * S] = acc[0];
#pragma unroll
        for (int j = 0; j < 12; ++j) acc[j] = acc[j + 1];
        acc[12] = make_float4(0.f, 0.f, 0.f, 0.f);
    }
}

extern "C" void kernel_launch(void* const* d_in, const int* in_sizes, int n_in,
                              void* d_out, int out_size, void* d_ws, size_t ws_size,
                              hipStream_t stream) {
    const float* x = (const float*)d_in[0];
    float* out = (float*)d_out;
    float* tmp = (float*)d_ws;  // 56.6 MB scratch

    // Pass A: fused W+H, software-pipelined, x -> tmp
    blur_wh<<<1728, 256, 0, stream>>>((const float4*)x, (float4*)tmp);
    // Pass B: D axis (stride 9216 f4), tmp -> out
    col_blur<9216, 1769472, 9216><<<864, 128, 0, stream>>>((const float4*)tmp, (float4*)out);
}

// Round 8
// 65.310 us; speedup vs baseline: 1.0332x; 1.0141x over previous
//
#include <hip/hip_runtime.h>
#include <hip/hip_bf16.h>
#include <hip/hip_fp16.h>

// GaussianSmoothing (2,1,192,192,192) f32, separable K=13 sigma=2.
// fp16 intermediates to cut inter-pass bytes (err budget ~1.3e-3 << 5.8e-3).
// Pass 1 blur_w : one-shot W-blur, f32 x -> f16 tmp1 (pure TLP, cold read)
// Pass 2 colH   : H-axis rolling march, f16 tmp1 -> f16 tmp2 (L3-warm)
// Pass 3 colD   : D-axis rolling march, f16 tmp2 -> f32 d_out (L3-warm)

#define DIM 192
#define DIM2 (192 * 192)
#define NIMG 2
#define TOTAL (NIMG * DIM * DIM2)   // 14,155,776 floats
#define NQ (TOTAL / 4)              // 3,538,944 quads (4 elems each, 48/row)

#define GTAPS                                                     \
    constexpr float G[13] = {                                     \
        2.2159242e-03f, 8.7641505e-03f, 2.6995483e-02f,           \
        6.4758800e-02f, 1.2098536e-01f, 1.7603266e-01f,           \
        1.9947114e-01f, 1.7603266e-01f, 1.2098536e-01f,           \
        6.4758800e-02f, 2.6995483e-02f, 8.7641505e-03f,           \
        2.2159242e-03f };

// ---- half4 <-> float4 helpers (8B per quad) -------------------------------
__device__ __forceinline__ float4 ld_h4(const uint2* __restrict__ p) {
    uint2 u = *p;
    __half2 h0 = *(__half2*)&u.x;
    __half2 h1 = *(__half2*)&u.y;
    return make_float4(__low2float(h0), __high2float(h0),
                       __low2float(h1), __high2float(h1));
}
__device__ __forceinline__ uint2 st_h4(float4 v) {
    __half2 h0 = __floats2half2_rn(v.x, v.y);
    __half2 h1 = __floats2half2_rn(v.z, v.w);
    uint2 u;
    u.x = *(unsigned*)&h0;
    u.y = *(unsigned*)&h1;
    return u;
}

// ---------------------------------------------------------------------------
// Pass 1: W-blur, one f16-quad output per thread. 5 clamped/masked f4 loads
// from f32 input (all independent -> latency hidden by TLP alone).
// Grid = NQ/256 = 13824 blocks.
// ---------------------------------------------------------------------------
__global__ __launch_bounds__(256) void blur_w(const float4* __restrict__ in,
                                              uint2* __restrict__ out) {
    GTAPS
    const int q = blockIdx.x * 256 + threadIdx.x;   // global quad id
    const int xq = q % 48;
    const int rowbase = q - xq;

    float f[20];
#pragma unroll
    for (int d = 0; d < 5; ++d) {
        int qq = xq + d - 2;
        const float m = (qq >= 0 && qq < 48) ? 1.0f : 0.0f;
        qq = min(max(qq, 0), 47);
        float4 v = in[rowbase + qq];
        if (d != 2) { v.x *= m; v.y *= m; v.z *= m; v.w *= m; }
        *(float4*)&f[d * 4] = v;
    }

    float4 o;
    float* op = &o.x;
#pragma unroll
    for (int j = 0; j < 4; ++j) {
        float a = 0.0f;
#pragma unroll
        for (int k = 0; k < 13; ++k) a += G[k] * f[j + k + 2];
        op[j] = a;
    }
    out[q] = st_h4(o);
}

// ---------------------------------------------------------------------------
// Passes 2/3: axis march with quad-stride S (quads of 4 elems; 48/row).
// Thread owns one quad-column, marches 32 outputs (+12 halo) with 13 rolling
// float4 accumulators (f32 math; f16 in; f16 or f32 out).
//   column c: base = (c / Q) * M + (c % Q)
//   H: Q=48, M=9216, S=48     D: Q=9216, M=1769472, S=9216
// ncols = 18432; chunks = 6; block = 128 -> grid = 864.
// ---------------------------------------------------------------------------
template <int Q, int M, int S, bool OUT_F32>
__global__ __launch_bounds__(128) void col_blur(const uint2* __restrict__ in,
                                                void* __restrict__ out_) {
    GTAPS
    uint2* __restrict__ out16 = (uint2*)out_;
    float4* __restrict__ out32 = (float4*)out_;
    const int gt = blockIdx.x * 128 + threadIdx.x;
    const int chunk = gt / 18432;          // uniform per block
    const int c = gt % 18432;
    const int base = (c / Q) * M + (c % Q);
    const int d0 = chunk * 32;

    float4 acc[13];
#pragma unroll
    for (int j = 0; j < 13; ++j) acc[j] = make_float4(0.f, 0.f, 0.f, 0.f);

#pragma unroll
    for (int s = 0; s < 44; ++s) {
        const int i = d0 - 6 + s;
        float4 v = make_float4(0.f, 0.f, 0.f, 0.f);
        if (i >= 0 && i < DIM) v = ld_h4(&in[base + i * S]);
#pragma unroll
        for (int j = 0; j < 13; ++j) {
            const float g = G[12 - j];
            acc[j].x += g * v.x;
            acc[j].y += g * v.y;
            acc[j].z += g * v.z;
            acc[j].w += g * v.w;
        }
        if (s >= 12) {
            const int o = base + (i - 6) * S;
            if (OUT_F32) out32[o] = acc[0];
            else         out16[o] = st_h4(acc[0]);
        }
#pragma unroll
        for (int j = 0; j < 12; ++j) acc[j] = acc[j + 1];
        acc[12] = make_float4(0.f, 0.f, 0.f, 0.f);
    }
}

extern "C" void kernel_launch(void* const* d_in, const int* in_sizes, int n_in,
                              void* d_out, int out_size, void* d_ws, size_t ws_size,
                              hipStream_t stream) {
    const float* x = (const float*)d_in[0];
    float* out = (float*)d_out;
    uint2* tmp1 = (uint2*)d_ws;               // f16, 28.3 MB (NQ uint2)
    uint2* tmp2 = ((uint2*)d_ws) + NQ;        // f16, 28.3 MB

    // Pass 1: W one-shot, f32 x -> f16 tmp1
    blur_w<<<NQ / 256, 256, 0, stream>>>((const float4*)x, tmp1);
    // Pass 2: H axis (stride 48 quads), f16 -> f16
    col_blur<48, 9216, 48, false><<<864, 128, 0, stream>>>(tmp1, (void*)tmp2);
    // Pass 3: D axis (stride 9216 quads), f16 -> f32 out
    col_blur<9216, 1769472, 9216, true><<<864, 128, 0, stream>>>(tmp2, (void*)out);
}

// Round 9
// 53.461 us; speedup vs baseline: 1.2622x; 1.2216x over previous
//
#include <hip/hip_runtime.h>
#include <hip/hip_bf16.h>
#include <hip/hip_fp16.h>

// GaussianSmoothing (2,1,192,192,192) f32, separable K=13 sigma=2.
// fp16 intermediates; 3 passes:
// Pass 1 blur_w : one-shot W-blur, 2 quads (8 floats) per thread,
//                 6 f4 loads -> 1 uint4 (4x f16 quad... 8 halves) store.
//                 f32 x -> f16 tmp1   (cold read, pure TLP)
// Pass 2 colH   : H-axis rolling march CH=16, f16 tmp1 -> f16 tmp2 (L3-warm)
// Pass 3 colD   : D-axis rolling march CH=16, f16 tmp2 -> f32 d_out (L3-warm)

#define DIM 192
#define DIM2 (192 * 192)
#define NIMG 2
#define TOTAL (NIMG * DIM * DIM2)   // 14,155,776 floats
#define NQ (TOTAL / 4)              // 3,538,944 quads (4 elems, 48 per row)
#define NP (NQ / 2)                 // 1,769,472 quad-pairs (24 per row)

#define GTAPS                                                     \
    constexpr float G[13] = {                                     \
        2.2159242e-03f, 8.7641505e-03f, 2.6995483e-02f,           \
        6.4758800e-02f, 1.2098536e-01f, 1.7603266e-01f,           \
        1.9947114e-01f, 1.7603266e-01f, 1.2098536e-01f,           \
        6.4758800e-02f, 2.6995483e-02f, 8.7641505e-03f,           \
        2.2159242e-03f };

// ---- half4 <-> float4 helpers (8B per quad) -------------------------------
__device__ __forceinline__ float4 ld_h4(const uint2* __restrict__ p) {
    uint2 u = *p;
    __half2 h0 = *(__half2*)&u.x;
    __half2 h1 = *(__half2*)&u.y;
    return make_float4(__low2float(h0), __high2float(h0),
                       __low2float(h1), __high2float(h1));
}
__device__ __forceinline__ uint2 st_h4(float4 v) {
    __half2 h0 = __floats2half2_rn(v.x, v.y);
    __half2 h1 = __floats2half2_rn(v.z, v.w);
    uint2 u;
    u.x = *(unsigned*)&h0;
    u.y = *(unsigned*)&h1;
    return u;
}

// ---------------------------------------------------------------------------
// Pass 1: W-blur, TWO quads (8 floats) per thread. Window = 6 quads
// [2jp-2 .. 2jp+3] of the row, clamped + 0/1-masked (branch-free). One
// 16B uint4 store of 8 f16 values. 3 VMEM loads + 0.5 store per output quad.
// Grid = NP/256 = 6912 blocks.
// ---------------------------------------------------------------------------
__global__ __launch_bounds__(256) void blur_w(const float4* __restrict__ in,
                                              uint4* __restrict__ out) {
    GTAPS
    const int j = blockIdx.x * 256 + threadIdx.x;   // pair id
    const int jp = j % 24;                          // pair within row
    const int rowq = (j / 24) * 48;                 // row base, quad units

    // f[m] = rowfloat[8*jp - 8 + m], m = 0..23 (zero outside row)
    float f[24];
#pragma unroll
    for (int d = 0; d < 6; ++d) {
        int qq = 2 * jp - 2 + d;
        const float m = (qq >= 0 && qq < 48) ? 1.0f : 0.0f;
        qq = min(max(qq, 0), 47);
        float4 v = in[rowq + qq];
        if (d < 2 || d > 3) {                       // d=2,3 always valid
            v.x *= m; v.y *= m; v.z *= m; v.w *= m;
        }
        *(float4*)&f[d * 4] = v;
    }

    float o[8];
#pragma unroll
    for (int t = 0; t < 8; ++t) {
        float a = 0.0f;
#pragma unroll
        for (int k = 0; k < 13; ++k) a += G[k] * f[t + 2 + k];
        o[t] = a;
    }
    uint4 r;
    {
        uint2 lo = st_h4(make_float4(o[0], o[1], o[2], o[3]));
        uint2 hi = st_h4(make_float4(o[4], o[5], o[6], o[7]));
        r.x = lo.x; r.y = lo.y; r.z = hi.x; r.w = hi.y;
    }
    out[j] = r;
}

// ---------------------------------------------------------------------------
// Passes 2/3: axis march with quad-stride S (quad = 4 elems; 48/row).
// Thread owns one quad-column, marches CHUNK=16 outputs (+12 halo = 28 steps)
// with 13 rolling float4 accumulators (f32 math; f16 in; f16 or f32 out).
//   column c: base = (c / Q) * M + (c % Q)
//   H: Q=48, M=9216, S=48     D: Q=9216, M=1769472, S=9216
// ncols = 18432; chunks = 12; block = 128 -> grid = 1728 (3456 waves).
// ---------------------------------------------------------------------------
#define CHUNK 16
#define NSTEP (CHUNK + 12)   // 28
#define NCH (DIM / CHUNK)    // 12

template <int Q, int M, int S, bool OUT_F32>
__global__ __launch_bounds__(128) void col_blur(const uint2* __restrict__ in,
                                                void* __restrict__ out_) {
    GTAPS
    uint2* __restrict__ out16 = (uint2*)out_;
    float4* __restrict__ out32 = (float4*)out_;
    const int gt = blockIdx.x * 128 + threadIdx.x;
    const int chunk = gt / 18432;          // uniform per block (18432%128==0)
    const int c = gt % 18432;
    const int base = (c / Q) * M + (c % Q);
    const int d0 = chunk * CHUNK;

    float4 acc[13];
#pragma unroll
    for (int j = 0; j < 13; ++j) acc[j] = make_float4(0.f, 0.f, 0.f, 0.f);

#pragma unroll
    for (int s = 0; s < NSTEP; ++s) {
        const int i = d0 - 6 + s;
        float4 v = make_float4(0.f, 0.f, 0.f, 0.f);
        if (i >= 0 && i < DIM) v = ld_h4(&in[base + i * S]);
#pragma unroll
        for (int j = 0; j < 13; ++j) {
            const float g = G[12 - j];
            acc[j].x += g * v.x;
            acc[j].y += g * v.y;
            acc[j].z += g * v.z;
            acc[j].w += g * v.w;
        }
        if (s >= 12) {
            const int o = base + (i - 6) * S;
            if (OUT_F32) out32[o] = acc[0];
            else         out16[o] = st_h4(acc[0]);
        }
#pragma unroll
        for (int j = 0; j < 12; ++j) acc[j] = acc[j + 1];
        acc[12] = make_float4(0.f, 0.f, 0.f, 0.f);
    }
}

extern "C" void kernel_launch(void* const* d_in, const int* in_sizes, int n_in,
                              void* d_out, int out_size, void* d_ws, size_t ws_size,
                              hipStream_t stream) {
    const float* x = (const float*)d_in[0];
    float* out = (float*)d_out;
    uint2* tmp1 = (uint2*)d_ws;               // f16, 28.3 MB (NQ uint2)
    uint2* tmp2 = ((uint2*)d_ws) + NQ;        // f16, 28.3 MB

    // Pass 1: W one-shot (2 quads/thread), f32 x -> f16 tmp1
    blur_w<<<NP / 256, 256, 0, stream>>>((const float4*)x, (uint4*)tmp1);
    // Pass 2: H axis (stride 48 quads), f16 -> f16
    col_blur<48, 9216, 48, false><<<NCH * 144, 128, 0, stream>>>(tmp1, (void*)tmp2);
    // Pass 3: D axis (stride 9216 quads), f16 -> f32 out
    col_blur<9216, 1769472, 9216, true><<<NCH * 144, 128, 0, stream>>>(tmp2, (void*)out);
}